// Round 6
// baseline (183.861 us; speedup 1.0000x reference)
//
#include <hip/hip_runtime.h>
#include <math.h>

// Net: 4 layers of out = 0.8*(x@W^T) + 0.2*max_i(W[o,i]*x[b,i]) + b
// B=1024, dims 256 -> 512 -> 512 -> 512 -> 1. All fp32.
//
// R6: R5 fused structure + packed-fp32 math.
//  - v_pk_mul_f32 / v_pk_add_f32 via float ext_vector_type(2) arithmetic
//  - v_max3_f32 via nested fmaxf  => 6 VALU instr per (k4-group x row) vs 12
//  - 4-stage h-register software pipeline (load->use ~3 stages ahead)
//  - 8-deep W prefetch ring from pre-transposed coalesced panels in d_ws
// h stays in LDS as wave-uniform float4 broadcasts (bank-conflict-free).

#define NT   512
#define ROWS 4

typedef float v2f __attribute__((ext_vector_type(2)));

// ws layout in float4 units
#define WT1_OFF 0
#define WT2_OFF 33280    // 32768 + 512 pad
#define WT3_OFF 99328    // 33280 + 65536 + 512 pad

__global__ __launch_bounds__(256) void transpose_all(
    const float* __restrict__ W1, const float* __restrict__ W2,
    const float* __restrict__ W3, float4* __restrict__ ws)
{
    const int tid = blockIdx.x * 256 + threadIdx.x;   // 0 .. 163839
    const float* W;
    float4* WT;
    int o, k4, K;
    if (tid < 32768) {                    // W1: O=512, K=256, K4=64
        W = W1; WT = ws + WT1_OFF; K = 256;
        o = tid >> 6; k4 = tid & 63;
    } else if (tid < 98304) {             // W2: O=512, K=512, K4=128
        const int idx = tid - 32768;
        W = W2; WT = ws + WT2_OFF; K = 512;
        o = idx >> 7; k4 = idx & 127;
    } else {                              // W3: O=512, K=512, K4=128
        const int idx = tid - 98304;
        W = W3; WT = ws + WT3_OFF; K = 512;
        o = idx >> 7; k4 = idx & 127;
    }
    float4 v = *(const float4*)&W[(size_t)o * K + 4 * k4];
    WT[(size_t)k4 * 512 + o] = v;
}

// ---- one k4-group of compute: 4 rows, packed fp32 + max3 ----
#define COMPUTE_K4(wv, H)                                                   \
    {                                                                       \
        v2f w01; w01[0] = (wv).x; w01[1] = (wv).y;                          \
        v2f w23; w23[0] = (wv).z; w23[1] = (wv).w;                          \
        _Pragma("unroll")                                                   \
        for (int r = 0; r < ROWS; ++r) {                                    \
            v2f h01; h01[0] = H[r].x; h01[1] = H[r].y;                      \
            v2f h23; h23[0] = H[r].z; h23[1] = H[r].w;                      \
            v2f p01 = w01 * h01;                                            \
            v2f p23 = w23 * h23;                                            \
            sA[r] += p01;                                                   \
            sB[r] += p23;                                                   \
            mA[r] = fmaxf(fmaxf(mA[r], p01[0]), p01[1]);                    \
            mB[r] = fmaxf(fmaxf(mB[r], p23[0]), p23[1]);                    \
        }                                                                   \
    }

#define LOADH(H, k4idx)                                                     \
    {                                                                       \
        _Pragma("unroll")                                                   \
        for (int r = 0; r < ROWS; ++r)                                      \
            H[r] = *(const float4*)&hin[r][(k4idx) * 4];                    \
    }

template<int K4>
__device__ __forceinline__ void layer_bcast(
    const float (*__restrict__ hin)[512],
    float (*__restrict__ hout)[512],
    const float4* __restrict__ WT,    // [K4][512] coalesced panels
    const float* __restrict__ bias,
    int t)
{
    v2f sA[ROWS], sB[ROWS];
    float mA[ROWS], mB[ROWS];
    #pragma unroll
    for (int r = 0; r < ROWS; ++r) {
        sA[r] = (v2f)0.f; sB[r] = (v2f)0.f;
        mA[r] = -INFINITY; mB[r] = -INFINITY;
    }

    const float4* wp = WT + t;

    // 8-deep W prefetch ring (K4 >= 8 always)
    float4 wreg[8];
    #pragma unroll
    for (int i = 0; i < 8; ++i) wreg[i] = wp[(size_t)i * 512];

    // 4-stage h pipeline
    float4 hP0[ROWS], hP1[ROWS], hP2[ROWS], hP3[ROWS];
    LOADH(hP0, 0); LOADH(hP1, 1); LOADH(hP2, 2); LOADH(hP3, 3);

    #pragma unroll 1
    for (int kg = 0; kg < K4; kg += 4) {
        // stage 0
        {
            float4 wv = wreg[kg & 7];
            if (kg + 8 < K4) wreg[kg & 7] = wp[(size_t)(kg + 8) * 512];
            COMPUTE_K4(wv, hP0);
            if (kg + 4 < K4) LOADH(hP0, kg + 4);
        }
        // stage 1
        {
            float4 wv = wreg[(kg + 1) & 7];
            if (kg + 9 < K4) wreg[(kg + 1) & 7] = wp[(size_t)(kg + 9) * 512];
            COMPUTE_K4(wv, hP1);
            if (kg + 5 < K4) LOADH(hP1, kg + 5);
        }
        // stage 2
        {
            float4 wv = wreg[(kg + 2) & 7];
            if (kg + 10 < K4) wreg[(kg + 2) & 7] = wp[(size_t)(kg + 10) * 512];
            COMPUTE_K4(wv, hP2);
            if (kg + 6 < K4) LOADH(hP2, kg + 6);
        }
        // stage 3
        {
            float4 wv = wreg[(kg + 3) & 7];
            if (kg + 11 < K4) wreg[(kg + 3) & 7] = wp[(size_t)(kg + 11) * 512];
            COMPUTE_K4(wv, hP3);
            if (kg + 7 < K4) LOADH(hP3, kg + 7);
        }
    }

    const float bo = bias[t];
    #pragma unroll
    for (int r = 0; r < ROWS; ++r) {
        v2f sv = sA[r] + sB[r];
        float s = sv[0] + sv[1];
        float m = fmaxf(mA[r], mB[r]);
        hout[r][t] = fmaf(0.2f, m, fmaf(0.8f, s, bo));
    }
}

__global__ __launch_bounds__(NT, 2) void net_fused(
    const float* __restrict__ x,
    const float4* __restrict__ WT1, const float* __restrict__ b1,
    const float4* __restrict__ WT2, const float* __restrict__ b2,
    const float4* __restrict__ WT3, const float* __restrict__ b3,
    const float* __restrict__ W4,   const float* __restrict__ b4,
    float* __restrict__ out)
{
    __shared__ __align__(16) float ha[ROWS][512];
    __shared__ __align__(16) float hb[ROWS][512];
    __shared__ float red_s[8][ROWS];
    __shared__ float red_m[8][ROWS];

    const int t = threadIdx.x;
    const int row0 = blockIdx.x * ROWS;

    // stage x rows (4 x 256) into ha: one float2 per thread
    {
        const int r = t >> 7;
        const int c = (t & 127) * 2;
        float2 v = *(const float2*)&x[(size_t)(row0 + r) * 256 + c];
        ha[r][c]     = v.x;
        ha[r][c + 1] = v.y;
    }
    __syncthreads();

    layer_bcast<64> (ha, hb, WT1, b1, t);   // x  -> h1
    __syncthreads();
    layer_bcast<128>(hb, ha, WT2, b2, t);   // h1 -> h2
    __syncthreads();
    layer_bcast<128>(ha, hb, WT3, b3, t);   // h2 -> h3
    __syncthreads();

    // ---- layer 4: O=1 ----
    const float w4 = W4[t];
    float ps[ROWS], pm[ROWS];
    #pragma unroll
    for (int r = 0; r < ROWS; ++r) {
        float p = w4 * hb[r][t];
        ps[r] = p;
        pm[r] = p;
    }
    #pragma unroll
    for (int off = 32; off; off >>= 1) {
        #pragma unroll
        for (int r = 0; r < ROWS; ++r) {
            ps[r] += __shfl_xor(ps[r], off, 64);
            pm[r] = fmaxf(pm[r], __shfl_xor(pm[r], off, 64));
        }
    }
    const int lane = t & 63;
    const int wave = t >> 6;
    if (lane == 0) {
        #pragma unroll
        for (int r = 0; r < ROWS; ++r) {
            red_s[wave][r] = ps[r];
            red_m[wave][r] = pm[r];
        }
    }
    __syncthreads();

    if (t < ROWS) {
        float s = red_s[0][t];
        float m = red_m[0][t];
        #pragma unroll
        for (int w = 1; w < 8; ++w) {
            s += red_s[w][t];
            m = fmaxf(m, red_m[w][t]);
        }
        out[row0 + t] = fmaf(0.2f, m, fmaf(0.8f, s, b4[0]));
    }
}

extern "C" void kernel_launch(void* const* d_in, const int* in_sizes, int n_in,
                              void* d_out, int out_size, void* d_ws, size_t ws_size,
                              hipStream_t stream)
{
    const float* x  = (const float*)d_in[0];
    const float* W1 = (const float*)d_in[1];
    const float* b1 = (const float*)d_in[2];
    const float* W2 = (const float*)d_in[3];
    const float* b2 = (const float*)d_in[4];
    const float* W3 = (const float*)d_in[5];
    const float* b3 = (const float*)d_in[6];
    const float* W4 = (const float*)d_in[7];
    const float* b4 = (const float*)d_in[8];

    float4* ws4 = (float4*)d_ws;

    transpose_all<<<640, 256, 0, stream>>>(W1, W2, W3, ws4);

    net_fused<<<256, NT, 0, stream>>>(
        x,
        ws4 + WT1_OFF, b1,
        ws4 + WT2_OFF, b2,
        ws4 + WT3_OFF, b3,
        W4, b4,
        (float*)d_out);
}

// Round 7
// 58.623 us; speedup vs baseline: 3.1363x; 3.1363x over previous
//
#include <hip/hip_runtime.h>
#include <math.h>

// Net: 4 layers of out = 0.8*(x@W^T) + 0.2*max_i(W[o,i]*x[b,i]) + b
// B=1024, dims 256 -> 512 -> 512 -> 512 -> 1. All fp32.
//
// R7 = R5 structure (67us, named-register prefetch, NO runtime-indexed
// register arrays -- R6's wreg[kg&7] went to scratch: WRITE_SIZE 300MB)
// + packed fp32 arithmetic:
//   v2f (*,+)  -> v_pk_mul_f32 / v_pk_add_f32
//   nested fmaxf -> v_max3_f32
// = 6 VALU instr per (k4-group x row) instead of 12.
// h stays in LDS as wave-uniform float4 broadcasts; W from pre-transposed
// coalesced panels in d_ws.

#define NT   512
#define ROWS 4

typedef float v2f __attribute__((ext_vector_type(2)));

// ws layout in float4 units
#define WT1_OFF 0
#define WT2_OFF 33280    // 32768 + 512 pad
#define WT3_OFF 99328    // 33280 + 65536 + 512 pad

__global__ __launch_bounds__(256) void transpose_all(
    const float* __restrict__ W1, const float* __restrict__ W2,
    const float* __restrict__ W3, float4* __restrict__ ws)
{
    const int tid = blockIdx.x * 256 + threadIdx.x;   // 0 .. 163839
    const float* W;
    float4* WT;
    int o, k4, K;
    if (tid < 32768) {                    // W1: O=512, K=256, K4=64
        W = W1; WT = ws + WT1_OFF; K = 256;
        o = tid >> 6; k4 = tid & 63;
    } else if (tid < 98304) {             // W2: O=512, K=512, K4=128
        const int idx = tid - 32768;
        W = W2; WT = ws + WT2_OFF; K = 512;
        o = idx >> 7; k4 = idx & 127;
    } else {                              // W3: O=512, K=512, K4=128
        const int idx = tid - 98304;
        W = W3; WT = ws + WT3_OFF; K = 512;
        o = idx >> 7; k4 = idx & 127;
    }
    float4 v = *(const float4*)&W[(size_t)o * K + 4 * k4];
    WT[(size_t)k4 * 512 + o] = v;
}

// One layer: thread t owns output neuron o=t for ROWS batch rows.
// W from global (coalesced panel), h from LDS (wave-uniform broadcast).
__device__ __forceinline__ void layer_bcast(
    const float (*__restrict__ hin)[512],
    float (*__restrict__ hout)[512],
    const float4* __restrict__ WT,    // [K4][512]
    const float* __restrict__ bias,
    int K4, int t)
{
    v2f sA[ROWS], sB[ROWS];
    float mA[ROWS], mB[ROWS];
    #pragma unroll
    for (int r = 0; r < ROWS; ++r) {
        sA[r] = (v2f)0.f; sB[r] = (v2f)0.f;
        mA[r] = -INFINITY; mB[r] = -INFINITY;
    }

    const float4* wp = WT + t;
    float4 w0 = wp[0];
    float4 w1 = wp[512];
    float4 w2 = wp[1024];
    float4 w3 = wp[1536];

    for (int kg = 0; kg < K4; kg += 4) {
        float4 n0 = w0, n1 = w1, n2 = w2, n3 = w3;
        if (kg + 4 < K4) {                 // uniform (scalar) branch
            const float4* q = wp + (size_t)(kg + 4) * 512;
            n0 = q[0];
            n1 = q[512];
            n2 = q[1024];
            n3 = q[1536];
        }
        #pragma unroll
        for (int j = 0; j < 4; ++j) {
            const float4 w = (j == 0) ? w0 : (j == 1) ? w1 : (j == 2) ? w2 : w3;
            const int k = (kg + j) * 4;
            v2f w01; w01[0] = w.x; w01[1] = w.y;
            v2f w23; w23[0] = w.z; w23[1] = w.w;
            #pragma unroll
            for (int r = 0; r < ROWS; ++r) {
                float4 h = *(const float4*)&hin[r][k];   // wave-uniform bcast
                v2f h01; h01[0] = h.x; h01[1] = h.y;
                v2f h23; h23[0] = h.z; h23[1] = h.w;
                v2f p01 = w01 * h01;                     // v_pk_mul_f32
                v2f p23 = w23 * h23;
                sA[r] += p01;                            // v_pk_add_f32
                sB[r] += p23;
                mA[r] = fmaxf(fmaxf(mA[r], p01[0]), p01[1]);   // v_max3_f32
                mB[r] = fmaxf(fmaxf(mB[r], p23[0]), p23[1]);
            }
        }
        w0 = n0; w1 = n1; w2 = n2; w3 = n3;
    }

    const float bo = bias[t];
    #pragma unroll
    for (int r = 0; r < ROWS; ++r) {
        v2f sv = sA[r] + sB[r];
        float s = sv[0] + sv[1];
        float m = fmaxf(mA[r], mB[r]);
        hout[r][t] = fmaf(0.2f, m, fmaf(0.8f, s, bo));
    }
}

__global__ __launch_bounds__(NT) void net_fused(
    const float* __restrict__ x,
    const float4* __restrict__ WT1, const float* __restrict__ b1,
    const float4* __restrict__ WT2, const float* __restrict__ b2,
    const float4* __restrict__ WT3, const float* __restrict__ b3,
    const float* __restrict__ W4,   const float* __restrict__ b4,
    float* __restrict__ out)
{
    __shared__ __align__(16) float ha[ROWS][512];
    __shared__ __align__(16) float hb[ROWS][512];
    __shared__ float red_s[8][ROWS];
    __shared__ float red_m[8][ROWS];

    const int t = threadIdx.x;
    const int row0 = blockIdx.x * ROWS;

    // stage x rows (4 x 256) into ha: one float2 per thread
    {
        const int r = t >> 7;
        const int c = (t & 127) * 2;
        float2 v = *(const float2*)&x[(size_t)(row0 + r) * 256 + c];
        ha[r][c]     = v.x;
        ha[r][c + 1] = v.y;
    }
    __syncthreads();

    layer_bcast(ha, hb, WT1, b1, 64,  t);   // x  -> h1
    __syncthreads();
    layer_bcast(hb, ha, WT2, b2, 128, t);   // h1 -> h2
    __syncthreads();
    layer_bcast(ha, hb, WT3, b3, 128, t);   // h2 -> h3
    __syncthreads();

    // ---- layer 4: O=1 ----
    const float w4 = W4[t];
    float ps[ROWS], pm[ROWS];
    #pragma unroll
    for (int r = 0; r < ROWS; ++r) {
        float p = w4 * hb[r][t];
        ps[r] = p;
        pm[r] = p;
    }
    #pragma unroll
    for (int off = 32; off; off >>= 1) {
        #pragma unroll
        for (int r = 0; r < ROWS; ++r) {
            ps[r] += __shfl_xor(ps[r], off, 64);
            pm[r] = fmaxf(pm[r], __shfl_xor(pm[r], off, 64));
        }
    }
    const int lane = t & 63;
    const int wave = t >> 6;
    if (lane == 0) {
        #pragma unroll
        for (int r = 0; r < ROWS; ++r) {
            red_s[wave][r] = ps[r];
            red_m[wave][r] = pm[r];
        }
    }
    __syncthreads();

    if (t < ROWS) {
        float s = red_s[0][t];
        float m = red_m[0][t];
        #pragma unroll
        for (int w = 1; w < 8; ++w) {
            s += red_s[w][t];
            m = fmaxf(m, red_m[w][t]);
        }
        out[row0 + t] = fmaf(0.2f, m, fmaf(0.8f, s, b4[0]));
    }
}

extern "C" void kernel_launch(void* const* d_in, const int* in_sizes, int n_in,
                              void* d_out, int out_size, void* d_ws, size_t ws_size,
                              hipStream_t stream)
{
    const float* x  = (const float*)d_in[0];
    const float* W1 = (const float*)d_in[1];
    const float* b1 = (const float*)d_in[2];
    const float* W2 = (const float*)d_in[3];
    const float* b2 = (const float*)d_in[4];
    const float* W3 = (const float*)d_in[5];
    const float* b3 = (const float*)d_in[6];
    const float* W4 = (const float*)d_in[7];
    const float* b4 = (const float*)d_in[8];

    float4* ws4 = (float4*)d_ws;

    transpose_all<<<640, 256, 0, stream>>>(W1, W2, W3, ws4);

    net_fused<<<256, NT, 0, stream>>>(
        x,
        ws4 + WT1_OFF, b1,
        ws4 + WT2_OFF, b2,
        ws4 + WT3_OFF, b3,
        W4, b4,
        (float*)d_out);
}